// Round 11
// baseline (194.540 us; speedup 1.0000x reference)
//
#include <hip/hip_runtime.h>
#include <hip/hip_fp16.h>

#define DIM 64
#define PSHIFT 14          // panel = idx >> 14  (8 panels x 16384 nodes, 2MB fp16 each)
#define NPAN 8
#define NR 4               // rows per 8-lane group in sweep
#define SWEEP_BLOCKS 1024  // 4 blocks/CU, co-resident

// ---------- pass 1: compress x (f32) -> xh (fp16) ----------
__global__ __launch_bounds__(256) void cvt_half_kernel(
    const float* __restrict__ x, __half* __restrict__ xh, int n4)
{
    int i = blockIdx.x * blockDim.x + threadIdx.x;
    const int stride = gridDim.x * blockDim.x;
    for (; i < n4; i += stride) {
        const float4 v = ((const float4*)x)[i];
        __half2 h0 = __floats2half2_rn(v.x, v.y);
        __half2 h1 = __floats2half2_rn(v.z, v.w);
        uint2 u;
        u.x = *(const unsigned int*)&h0;
        u.y = *(const unsigned int*)&h1;
        ((uint2*)xh)[i] = u;
    }
}

// ---------- pass 2: stable per-row bucket sort of (idx,val) by panel ----------
// 16 lanes per row (4 rows per wave). Two chunked passes: count panels via
// segmented ballots, then rank-and-scatter. All per-lane state in named scalars.
__global__ __launch_bounds__(256) void bucket_kernel(
    const int*   __restrict__ indptr,
    const int*   __restrict__ indices,
    const float* __restrict__ values,
    uint2*       __restrict__ spair,
    int n_nodes)
{
    const int wave = (int)((blockIdx.x * blockDim.x + threadIdx.x) >> 6);
    const int lane = (int)(threadIdx.x & 63);
    const int sub  = lane >> 4;          // sub-row 0..3 within wave
    const int sl   = lane & 15;          // lane within 16-lane segment
    const int row  = wave * 4 + sub;

    int s = 0, e = 0;
    if (row < n_nodes) { s = indptr[row]; e = indptr[row + 1]; }
    const int shift = sub * 16;
    const unsigned below = (1u << sl) - 1u;

#define SEGB(P) ((unsigned)((__ballot(key == (P)) >> shift) & 0xFFFFull))

    // pass A: per-panel counts
    int c0=0,c1=0,c2=0,c3=0,c4=0,c5=0,c6=0,c7=0;
    for (int base = s; base < e; base += 16) {
        const int kk = base + sl;
        const bool val = kk < e;
        const int key = val ? (indices[kk] >> PSHIFT) : NPAN;
        c0 += __popc(SEGB(0)); c1 += __popc(SEGB(1));
        c2 += __popc(SEGB(2)); c3 += __popc(SEGB(3));
        c4 += __popc(SEGB(4)); c5 += __popc(SEGB(5));
        c6 += __popc(SEGB(6)); c7 += __popc(SEGB(7));
    }
    // exclusive prefix -> running cursors
    int u0 = 0;
    int u1 = c0;
    int u2 = u1 + c1;
    int u3 = u2 + c2;
    int u4 = u3 + c3;
    int u5 = u4 + c4;
    int u6 = u5 + c5;
    int u7 = u6 + c6;

    // pass B: rank within chunk-segment and scatter
    for (int base = s; base < e; base += 16) {
        const int kk = base + sl;
        const bool val = kk < e;
        const int c = val ? indices[kk] : 0;
        const float v = val ? values[kk] : 0.0f;
        const int key = val ? (c >> PSHIFT) : NPAN;
        const unsigned m0 = SEGB(0), m1 = SEGB(1), m2 = SEGB(2), m3 = SEGB(3);
        const unsigned m4 = SEGB(4), m5 = SEGB(5), m6 = SEGB(6), m7 = SEGB(7);
        unsigned mk = m0; int uk = u0;
        mk = (key==1)?m1:mk; uk = (key==1)?u1:uk;
        mk = (key==2)?m2:mk; uk = (key==2)?u2:uk;
        mk = (key==3)?m3:mk; uk = (key==3)?u3:uk;
        mk = (key==4)?m4:mk; uk = (key==4)?u4:uk;
        mk = (key==5)?m5:mk; uk = (key==5)?u5:uk;
        mk = (key==6)?m6:mk; uk = (key==6)?u6:uk;
        mk = (key==7)?m7:mk; uk = (key==7)?u7:uk;
        if (val) {
            uint2 pr; pr.x = (unsigned)c; pr.y = __float_as_uint(v);
            spair[s + uk + (int)__popc(mk & below)] = pr;
        }
        u0 += __popc(m0); u1 += __popc(m1); u2 += __popc(m2); u3 += __popc(m3);
        u4 += __popc(m4); u5 += __popc(m5); u6 += __popc(m6); u7 += __popc(m7);
    }
#undef SEGB
}

// ---------- pass 3: panel sweep SpMM ----------
// 1024 co-resident blocks; 8-lane group owns <=NR rows with register
// accumulators a[NR][8]. Panels outermost: per round, each row consumes one
// edge iff it belongs to the current panel (branch-free predication). All
// blocks sweep panels in phase -> gathers hit a sliding ~2MB band (L2-local).
__global__ __launch_bounds__(256, 4) void sweep_kernel(
    const __half* __restrict__ xh,
    const int*    __restrict__ indptr,
    const uint2*  __restrict__ spair,
    float*        __restrict__ out,
    int n_nodes, int rows_pb)
{
    const int b  = blockIdx.x;
    const int gq = (int)(threadIdx.x >> 3);   // group 0..31
    const int t  = (int)(threadIdx.x & 7);    // column octet
    const int rbase = b * rows_pb;

    int kk[NR], ke[NR];
    float a[NR][8];
#pragma unroll
    for (int i = 0; i < NR; ++i) {
        const int rl = gq + 32 * i;
        const int r  = rbase + rl;
        const bool ok = (rl < rows_pb) && (r < n_nodes);
        kk[i] = ok ? indptr[r] : 0;
        ke[i] = ok ? indptr[r + 1] : 0;
#pragma unroll
        for (int j = 0; j < 8; ++j) a[i][j] = 0.f;
    }

    for (int p = 0; p < NPAN; ++p) {
        while (true) {
            uint2 pk[NR]; uint4 g[NR]; bool in[NR];
            bool anyl = false;
#pragma unroll
            for (int i = 0; i < NR; ++i) {       // peek (always-valid address)
                const int addr = (kk[i] < ke[i]) ? kk[i] : 0;
                pk[i] = spair[addr];
            }
#pragma unroll
            for (int i = 0; i < NR; ++i) {       // predicated gather
                in[i] = (kk[i] < ke[i]) && ((int)(pk[i].x >> PSHIFT) == p);
                const unsigned cu = in[i] ? pk[i].x : 0u;
                g[i] = *(const uint4*)(xh + ((size_t)cu << 6) + (t << 3));
            }
#pragma unroll
            for (int i = 0; i < NR; ++i) {       // FMA + advance
                const float vv = in[i] ? __uint_as_float(pk[i].y) : 0.f;
                const __half* h = (const __half*)&g[i];
#pragma unroll
                for (int j = 0; j < 8; ++j) a[i][j] += __half2float(h[j]) * vv;
                kk[i] += in[i] ? 1 : 0;
                anyl = anyl || in[i];
            }
            if (!__any(anyl)) break;
        }
    }

#pragma unroll
    for (int i = 0; i < NR; ++i) {
        const int rl = gq + 32 * i;
        const int r  = rbase + rl;
        if ((rl < rows_pb) && (r < n_nodes)) {
            float4 r0; r0.x = a[i][0]; r0.y = a[i][1]; r0.z = a[i][2]; r0.w = a[i][3];
            float4 r1; r1.x = a[i][4]; r1.y = a[i][5]; r1.z = a[i][6]; r1.w = a[i][7];
            float* dst = out + (((size_t)r) << 6) + (t << 3);
            *(float4*)(dst)     = r0;
            *(float4*)(dst + 4) = r1;
        }
    }
}

// ---------- champion fallback: unsorted fp16, one row per wave ----------
__global__ __launch_bounds__(256) void spmm_half_kernel(
    const __half* __restrict__ xh,
    const int*   __restrict__ indptr,
    const int*   __restrict__ indices,
    const float* __restrict__ values,
    float*       __restrict__ out,
    int n_nodes)
{
    const int row  = (int)((blockIdx.x * blockDim.x + threadIdx.x) >> 6);
    const int lane = (int)(threadIdx.x & 63);
    if (row >= n_nodes) return;
    const int g = lane >> 3;
    const int t = lane & 7;

    const int start = indptr[row];
    const int end   = indptr[row + 1];

    float a[8] = {0.f,0.f,0.f,0.f,0.f,0.f,0.f,0.f};

    if (start < end) {
        const int last = end - 1;
        for (int k = start; k < end; k += 16) {
            const int e0 = k + g;
            const int e1 = k + 8 + g;
            const int i0 = (e0 <= last) ? e0 : last;
            const int i1 = (e1 <= last) ? e1 : last;
            const int c0 = indices[i0];
            const int c1 = indices[i1];
            const float w0 = (e0 <= last) ? values[i0] : 0.0f;
            const float w1 = (e1 <= last) ? values[i1] : 0.0f;
            const uint4 p0 = *(const uint4*)(xh + (((unsigned)c0) << 6) + (t << 3));
            const uint4 p1 = *(const uint4*)(xh + (((unsigned)c1) << 6) + (t << 3));
            const __half* h0 = (const __half*)&p0;
            const __half* h1 = (const __half*)&p1;
#pragma unroll
            for (int j = 0; j < 8; ++j) a[j] += __half2float(h0[j]) * w0;
#pragma unroll
            for (int j = 0; j < 8; ++j) a[j] += __half2float(h1[j]) * w1;
        }
    }

#define RED(m) a[0]+=__shfl_xor(a[0],m); a[1]+=__shfl_xor(a[1],m); \
               a[2]+=__shfl_xor(a[2],m); a[3]+=__shfl_xor(a[3],m); \
               a[4]+=__shfl_xor(a[4],m); a[5]+=__shfl_xor(a[5],m); \
               a[6]+=__shfl_xor(a[6],m); a[7]+=__shfl_xor(a[7],m);
    RED(8) RED(16) RED(32)
#undef RED

    if (lane < 8) {
        float4 r0; r0.x=a[0]; r0.y=a[1]; r0.z=a[2]; r0.w=a[3];
        float4 r1; r1.x=a[4]; r1.y=a[5]; r1.z=a[6]; r1.w=a[7];
        float* dst = out + (((size_t)row) << 6) + (t << 3);
        *(float4*)(dst)     = r0;
        *(float4*)(dst + 4) = r1;
    }
}

// ---------- f32 fallback (ws too small) ----------
__global__ __launch_bounds__(256) void spmm_quad_kernel(
    const float* __restrict__ x,
    const int*   __restrict__ indptr,
    const int*   __restrict__ indices,
    const float* __restrict__ values,
    float*       __restrict__ out,
    int n_nodes)
{
    const int row  = (int)((blockIdx.x * blockDim.x + threadIdx.x) >> 6);
    const int lane = (int)(threadIdx.x & 63);
    if (row >= n_nodes) return;

    const int start = indptr[row];
    const int end   = indptr[row + 1];
    const int g     = lane >> 4;
    const unsigned col4 = (unsigned)(lane & 15) << 2;

    float ax = 0.f, ay = 0.f, az = 0.f, aw = 0.f;

    if (start < end) {
        const int last = end - 1;
        for (int k = start; k < end; k += 16) {
            const int e0 = k + 0 + g, e1 = k + 4 + g, e2 = k + 8 + g, e3 = k + 12 + g;
            const int ce0 = e0 <= last ? e0 : last;
            const int ce1 = e1 <= last ? e1 : last;
            const int ce2 = e2 <= last ? e2 : last;
            const int ce3 = e3 <= last ? e3 : last;
            const int c0 = indices[ce0], c1 = indices[ce1];
            const int c2 = indices[ce2], c3 = indices[ce3];
            const float w0 = (e0 <= last) ? values[ce0] : 0.0f;
            const float w1 = (e1 <= last) ? values[ce1] : 0.0f;
            const float w2 = (e2 <= last) ? values[ce2] : 0.0f;
            const float w3 = (e3 <= last) ? values[ce3] : 0.0f;
            const float4 a0 = *(const float4*)(x + (((unsigned)c0) << 6) + col4);
            const float4 a1 = *(const float4*)(x + (((unsigned)c1) << 6) + col4);
            const float4 a2 = *(const float4*)(x + (((unsigned)c2) << 6) + col4);
            const float4 a3 = *(const float4*)(x + (((unsigned)c3) << 6) + col4);
            ax += w0 * a0.x; ay += w0 * a0.y; az += w0 * a0.z; aw += w0 * a0.w;
            ax += w1 * a1.x; ay += w1 * a1.y; az += w1 * a1.z; aw += w1 * a1.w;
            ax += w2 * a2.x; ay += w2 * a2.y; az += w2 * a2.z; aw += w2 * a2.w;
            ax += w3 * a3.x; ay += w3 * a3.y; az += w3 * a3.z; aw += w3 * a3.w;
        }
    }

    ax += __shfl_xor(ax, 16); ay += __shfl_xor(ay, 16);
    az += __shfl_xor(az, 16); aw += __shfl_xor(aw, 16);
    ax += __shfl_xor(ax, 32); ay += __shfl_xor(ay, 32);
    az += __shfl_xor(az, 32); aw += __shfl_xor(aw, 32);

    if (lane < 16) {
        float4 r; r.x = ax; r.y = ay; r.z = az; r.w = aw;
        *(float4*)(out + ((size_t)row << 6) + col4) = r;
    }
}

extern "C" void kernel_launch(void* const* d_in, const int* in_sizes, int n_in,
                              void* d_out, int out_size, void* d_ws, size_t ws_size,
                              hipStream_t stream) {
    const float* x       = (const float*)d_in[0];
    const int*   indptr  = (const int*)  d_in[1];
    const int*   indices = (const int*)  d_in[2];
    const float* values  = (const float*)d_in[3];
    float*       out     = (float*)d_out;

    const int n_nodes = in_sizes[1] - 1;     // indptr has N+1 entries
    const int n_xelem = in_sizes[0];         // N * 64
    const int n_edges = in_sizes[2];

    const int threads = 256;
    const int rows_pb = (n_nodes + SWEEP_BLOCKS - 1) / SWEEP_BLOCKS;

    const size_t xh_bytes    = (size_t)n_xelem * sizeof(__half);
    const size_t spair_bytes = (size_t)n_edges * sizeof(uint2);

    const bool sweep_ok = (ws_size >= xh_bytes + spair_bytes) &&
                          (n_nodes <= (1 << (PSHIFT + 3))) &&   // panel id fits 3 bits
                          (rows_pb <= 32 * NR);                 // group slots cover block rows

    if (sweep_ok) {
        __half* xh    = (__half*)d_ws;
        uint2*  spair = (uint2*)((char*)d_ws + xh_bytes);

        cvt_half_kernel<<<2048, threads, 0, stream>>>(x, xh, n_xelem / 4);

        const int bwaves  = (n_nodes + 3) / 4;              // 4 rows per wave
        const int bblocks = (bwaves + 3) / 4;               // 4 waves per block
        bucket_kernel<<<bblocks, threads, 0, stream>>>(
            indptr, indices, values, spair, n_nodes);

        sweep_kernel<<<SWEEP_BLOCKS, threads, 0, stream>>>(
            xh, indptr, spair, out, n_nodes, rows_pb);
    } else if (ws_size >= xh_bytes) {
        __half* xh = (__half*)d_ws;
        cvt_half_kernel<<<2048, threads, 0, stream>>>(x, xh, n_xelem / 4);
        const int row_blocks = (n_nodes + 3) / 4;
        spmm_half_kernel<<<row_blocks, threads, 0, stream>>>(
            xh, indptr, indices, values, out, n_nodes);
    } else {
        const int row_blocks = (n_nodes + 3) / 4;
        spmm_quad_kernel<<<row_blocks, threads, 0, stream>>>(
            x, indptr, indices, values, out, n_nodes);
    }
}